// Round 1
// baseline (106645.093 us; speedup 1.0000x reference)
//
#include <hip/hip_runtime.h>
#include <hip/hip_bf16.h>

#define S_LEN 1024
#define BATCH 128
#define HDIM  256
#define IDIM  256

// Persistent fused LSTM.
// grid = 256 blocks (1 per CU, all co-resident -> flag spin is safe).
// bg = bid & 31  : batch group (4 batch rows)   [XCD-swizzle: group's 8 blocks share bid%32 -> same XCD]
// hs = bid >> 5  : h-slice of 32 rows
// block = 512 threads: tid = hl*16 + g*4 + kq   (hl 0..31, g 0..3, kq 0..3)
// Each thread pins Wh_g[hrow][kq*64..+64) and Wx_g[hrow][kq*64..+64) in VGPRs (128 floats).
// Per step: recurrent matvec partial (256 FMA) + gate exchange + elementwise, then
// x-projection for step t+1 (256 FMA) issued AFTER the flag release so it overlaps
// the inter-block flag latency. Sync: per-block monotonic flags, release/acquire, agent scope.

__global__ __launch_bounds__(512) void lstm_persist(
    const float* __restrict__ x,
    const float* __restrict__ Wxi, const float* __restrict__ Whi,
    const float* __restrict__ bxi, const float* __restrict__ bhi,
    const float* __restrict__ Wxf, const float* __restrict__ Whf,
    const float* __restrict__ bxf, const float* __restrict__ bhf,
    const float* __restrict__ Wxo, const float* __restrict__ Who,
    const float* __restrict__ bxo, const float* __restrict__ bho,
    const float* __restrict__ Wxc, const float* __restrict__ Whc,
    const float* __restrict__ bxc, const float* __restrict__ bhc,
    float* __restrict__ out,          // h_seq (S,B,H) then h(B,H) then c(B,H)
    float* __restrict__ hbuf,         // ws: 2 * B * H floats, zeroed
    unsigned int* __restrict__ flags) // ws: 256 u32, zeroed
{
  const int bid = blockIdx.x;
  const int bg  = bid & 31;
  const int hs  = bid >> 5;
  const int tid = threadIdx.x;
  const int hl  = tid >> 4;
  const int gg  = (tid >> 2) & 3;
  const int kq  = tid & 3;
  const int hrow = hs * 32 + hl;
  const int b0   = bg * 4;

  const float* Wh = (gg == 0) ? Whi : (gg == 1) ? Whf : (gg == 2) ? Who : Whc;
  const float* Wx = (gg == 0) ? Wxi : (gg == 1) ? Wxf : (gg == 2) ? Wxo : Wxc;
  const float* bx = (gg == 0) ? bxi : (gg == 1) ? bxf : (gg == 2) ? bxo : bxc;
  const float* bh = (gg == 0) ? bhi : (gg == 1) ? bhf : (gg == 2) ? bho : bhc;
  const float bias = bx[hrow] + bh[hrow];

  // Pin weight slices in VGPRs (static indexing only -> stays in registers).
  float wh[64], wx[64];
  {
    const float4* pwh = (const float4*)(Wh + hrow * HDIM + kq * 64);
    const float4* pwx = (const float4*)(Wx + hrow * IDIM + kq * 64);
#pragma unroll
    for (int j = 0; j < 16; ++j) {
      float4 a = pwh[j];
      wh[4*j+0] = a.x; wh[4*j+1] = a.y; wh[4*j+2] = a.z; wh[4*j+3] = a.w;
      float4 b = pwx[j];
      wx[4*j+0] = b.x; wx[4*j+1] = b.y; wx[4*j+2] = b.z; wx[4*j+3] = b.w;
    }
  }

  __shared__ float pre_ex[4][32][4];  // [b][hl][gate]

  // x-projection partial for t = 0
  float px[4];
  {
    const float* xb = x + (size_t)b0 * IDIM + kq * 64;
#pragma unroll
    for (int b = 0; b < 4; ++b) {
      const float4* p = (const float4*)(xb + b * IDIM);
      float acc = 0.f;
#pragma unroll
      for (int j = 0; j < 16; ++j) {
        float4 v = p[j];
        acc += wx[4*j+0] * v.x; acc += wx[4*j+1] * v.y;
        acc += wx[4*j+2] * v.z; acc += wx[4*j+3] * v.w;
      }
      px[b] = acc;
    }
  }

  float creg = 0.f, hreg = 0.f;

  for (int t = 0; t < S_LEN; ++t) {
    if (t > 0) {
      if (tid < 8) {
        const unsigned tgt = (unsigned)t;
        long cnt = 0;
        while (__hip_atomic_load(&flags[bg + 32 * tid], __ATOMIC_ACQUIRE,
                                 __HIP_MEMORY_SCOPE_AGENT) < tgt) {
          if (++cnt > 50000000L) break;  // bailout: wrong-but-terminating beats deadlock
        }
      }
      __syncthreads();
      __threadfence();  // acquire: invalidate L1 so h_buf reads see remote writes
    }

    // Recurrent matvec partials: ar[b] = sum_k wh[k] * h_prev[b][k-range]
    float ar[4];
    {
      const float* hb = hbuf + (size_t)((t & 1) ^ 1) * BATCH * HDIM
                             + (size_t)b0 * HDIM + kq * 64;
#pragma unroll
      for (int b = 0; b < 4; ++b) {
        const float4* p = (const float4*)(hb + b * HDIM);
        float acc = 0.f;
#pragma unroll
        for (int j = 0; j < 16; ++j) {
          float4 v = p[j];
          acc += wh[4*j+0] * v.x; acc += wh[4*j+1] * v.y;
          acc += wh[4*j+2] * v.z; acc += wh[4*j+3] * v.w;
        }
        ar[b] = acc;
      }
    }

    // Reduce the 4 k-quarters (lanes differ only in kq bits 0..1)
#pragma unroll
    for (int b = 0; b < 4; ++b) {
      float v = ar[b] + px[b];
      v += __shfl_xor(v, 1);
      v += __shfl_xor(v, 2);
      ar[b] = v;
    }
    if (kq == 0) {
#pragma unroll
      for (int b = 0; b < 4; ++b) pre_ex[b][hl][gg] = ar[b] + bias;
    }
    __syncthreads();

    if (tid < 128) {
      const int b = tid >> 5, h2 = tid & 31;
      float4 pg = *(const float4*)(&pre_ex[b][h2][0]);
      float ig = 1.f / (1.f + expf(-pg.x));
      float fg = 1.f / (1.f + expf(-pg.y));
      float og = 1.f / (1.f + expf(-pg.z));
      float cg = tanhf(pg.w);
      creg = fg * creg + ig * cg;
      hreg = og * tanhf(creg);
      const int bgl = b0 + b;
      const int hr  = hs * 32 + h2;
      hbuf[(size_t)(t & 1) * BATCH * HDIM + (size_t)bgl * HDIM + hr] = hreg;
      out[(size_t)t * BATCH * HDIM + (size_t)bgl * HDIM + hr] = hreg;
      __threadfence();  // release: drain h writes before flag
    }
    __syncthreads();
    if (tid == 0) {
      __hip_atomic_store(&flags[bid], (unsigned)(t + 1), __ATOMIC_RELEASE,
                         __HIP_MEMORY_SCOPE_AGENT);
    }

    // x-projection for step t+1 — overlaps remote flag propagation
    {
      const int tn = (t + 1 < S_LEN) ? (t + 1) : (S_LEN - 1);
      const float* xb = x + ((size_t)tn * BATCH + b0) * IDIM + kq * 64;
#pragma unroll
      for (int b = 0; b < 4; ++b) {
        const float4* p = (const float4*)(xb + b * IDIM);
        float acc = 0.f;
#pragma unroll
        for (int j = 0; j < 16; ++j) {
          float4 v = p[j];
          acc += wx[4*j+0] * v.x; acc += wx[4*j+1] * v.y;
          acc += wx[4*j+2] * v.z; acc += wx[4*j+3] * v.w;
        }
        px[b] = acc;
      }
    }
  }

  // Final (h, c) outputs
  if (tid < 128) {
    const int b = tid >> 5, h2 = tid & 31;
    const int bgl = b0 + b;
    const int hr  = hs * 32 + h2;
    float* oh = out + (size_t)S_LEN * BATCH * HDIM;
    oh[(size_t)bgl * HDIM + hr] = hreg;
    oh[(size_t)BATCH * HDIM + (size_t)bgl * HDIM + hr] = creg;
  }
}

extern "C" void kernel_launch(void* const* d_in, const int* in_sizes, int n_in,
                              void* d_out, int out_size, void* d_ws, size_t ws_size,
                              hipStream_t stream) {
  const float* x   = (const float*)d_in[0];
  const float* Wxi = (const float*)d_in[1];
  const float* Whi = (const float*)d_in[2];
  const float* bxi = (const float*)d_in[3];
  const float* bhi = (const float*)d_in[4];
  const float* Wxf = (const float*)d_in[5];
  const float* Whf = (const float*)d_in[6];
  const float* bxf = (const float*)d_in[7];
  const float* bhf = (const float*)d_in[8];
  const float* Wxo = (const float*)d_in[9];
  const float* Who = (const float*)d_in[10];
  const float* bxo = (const float*)d_in[11];
  const float* bho = (const float*)d_in[12];
  const float* Wxc = (const float*)d_in[13];
  const float* Whc = (const float*)d_in[14];
  const float* bxc = (const float*)d_in[15];
  const float* bhc = (const float*)d_in[16];

  float* out = (float*)d_out;
  float* hbuf = (float*)d_ws;
  unsigned int* flags = (unsigned int*)((char*)d_ws + (size_t)2 * BATCH * HDIM * sizeof(float));

  // zero h exchange buffers (h0 = 0) and flags; ws is re-poisoned 0xAA before every launch
  hipMemsetAsync(d_ws, 0,
                 (size_t)2 * BATCH * HDIM * sizeof(float) + 256 * sizeof(unsigned int),
                 stream);

  lstm_persist<<<dim3(256), dim3(512), 0, stream>>>(
      x, Wxi, Whi, bxi, bhi, Wxf, Whf, bxf, bhf,
      Wxo, Who, bxo, bho, Wxc, Whc, bxc, bhc,
      out, hbuf, flags);
}

// Round 3
// 43939.328 us; speedup vs baseline: 2.4271x; 2.4271x over previous
//
#include <hip/hip_runtime.h>
#include <hip/hip_bf16.h>

#define S_LEN 1024
#define BATCH 128
#define HDIM  256
#define IDIM  256

// Persistent fused LSTM, round 3 (= round 2 resubmitted; bench never ran due to
// GPU acquisition timeout).
// Sync design: ALL cross-block traffic (h exchange + flags) uses RELAXED
// agent-scope atomics (compile to global_load/store sc0 sc1 = L1/L2-bypass,
// write-through to the device coherence point). No acquire/release, no
// __threadfence() -> no buffer_wbl2 / buffer_inv whole-cache maintenance,
// which was 104us/step and 38GB of HBM thrash in round 1.
// Ordering: h-stores are drained by the s_waitcnt vmcnt(0) the compiler emits
// before __syncthreads' s_barrier; the flag store is issued after the barrier.
//
// grid = 256 blocks (1 per CU, co-resident -> spin is safe).
// bg = bid & 31 : batch group (4 batch rows); 8 blocks per group share bg.
// hs = bid >> 5 : h-slice of 32 rows.
// block = 512 threads: tid = hl*16 + g*4 + kq.
// Weights for the block's h-slice pinned in VGPRs (128 floats/thread).

__device__ __forceinline__ float2 ld_h2_bypass(const float* p) {
  unsigned long long u = __hip_atomic_load(
      (const unsigned long long*)p, __ATOMIC_RELAXED, __HIP_MEMORY_SCOPE_AGENT);
  float2 f;
  f.x = __uint_as_float((unsigned)(u & 0xffffffffULL));
  f.y = __uint_as_float((unsigned)(u >> 32));
  return f;
}

__global__ __launch_bounds__(512) void lstm_persist(
    const float* __restrict__ x,
    const float* __restrict__ Wxi, const float* __restrict__ Whi,
    const float* __restrict__ bxi, const float* __restrict__ bhi,
    const float* __restrict__ Wxf, const float* __restrict__ Whf,
    const float* __restrict__ bxf, const float* __restrict__ bhf,
    const float* __restrict__ Wxo, const float* __restrict__ Who,
    const float* __restrict__ bxo, const float* __restrict__ bho,
    const float* __restrict__ Wxc, const float* __restrict__ Whc,
    const float* __restrict__ bxc, const float* __restrict__ bhc,
    float* __restrict__ out,          // h_seq (S,B,H) then h(B,H) then c(B,H)
    float* __restrict__ hbuf,         // ws: 2 * B * H floats, zeroed
    unsigned int* __restrict__ flags) // ws: 256 u32, zeroed
{
  const int bid = blockIdx.x;
  const int bg  = bid & 31;
  const int hs  = bid >> 5;
  const int tid = threadIdx.x;
  const int hl  = tid >> 4;
  const int gg  = (tid >> 2) & 3;
  const int kq  = tid & 3;
  const int hrow = hs * 32 + hl;
  const int b0   = bg * 4;

  const float* Wh = (gg == 0) ? Whi : (gg == 1) ? Whf : (gg == 2) ? Who : Whc;
  const float* Wx = (gg == 0) ? Wxi : (gg == 1) ? Wxf : (gg == 2) ? Wxo : Wxc;
  const float* bx = (gg == 0) ? bxi : (gg == 1) ? bxf : (gg == 2) ? bxo : bxc;
  const float* bh = (gg == 0) ? bhi : (gg == 1) ? bhf : (gg == 2) ? bho : bhc;
  const float bias = bx[hrow] + bh[hrow];

  // Pin weight slices in registers (static indexing only).
  float wh[64], wx[64];
  {
    const float4* pwh = (const float4*)(Wh + hrow * HDIM + kq * 64);
    const float4* pwx = (const float4*)(Wx + hrow * IDIM + kq * 64);
#pragma unroll
    for (int j = 0; j < 16; ++j) {
      float4 a = pwh[j];
      wh[4*j+0] = a.x; wh[4*j+1] = a.y; wh[4*j+2] = a.z; wh[4*j+3] = a.w;
      float4 b = pwx[j];
      wx[4*j+0] = b.x; wx[4*j+1] = b.y; wx[4*j+2] = b.z; wx[4*j+3] = b.w;
    }
  }

  __shared__ float pre_ex[4][32][4];  // [b][hl][gate]

  // x-projection partial for t = 0 (normal cached loads: x is read-only input)
  float px[4];
  {
    const float* xb = x + (size_t)b0 * IDIM + kq * 64;
#pragma unroll
    for (int b = 0; b < 4; ++b) {
      const float4* p = (const float4*)(xb + b * IDIM);
      float acc = 0.f;
#pragma unroll
      for (int j = 0; j < 16; ++j) {
        float4 v = p[j];
        acc += wx[4*j+0] * v.x; acc += wx[4*j+1] * v.y;
        acc += wx[4*j+2] * v.z; acc += wx[4*j+3] * v.w;
      }
      px[b] = acc;
    }
  }

  float creg = 0.f, hreg = 0.f;

  for (int t = 0; t < S_LEN; ++t) {
    if (t > 0) {
      if (tid < 8) {
        const unsigned tgt = (unsigned)t;
        long cnt = 0;
        while (__hip_atomic_load(&flags[bg + 32 * tid], __ATOMIC_RELAXED,
                                 __HIP_MEMORY_SCOPE_AGENT) < tgt) {
          if (++cnt > 200000000L) break;  // bailout: terminating beats deadlock
        }
      }
      __syncthreads();  // no fence needed: h reads below bypass L1/L2 themselves
    }

    // Recurrent matvec partials: ar[b] = sum_k wh[k] * h_prev[b][k-range]
    // h loads are 8B relaxed agent atomics (sc0 sc1 -> read from coherence pt).
    float ar[4];
    {
      const float* hb = hbuf + (size_t)((t & 1) ^ 1) * BATCH * HDIM
                             + (size_t)b0 * HDIM + kq * 64;
#pragma unroll
      for (int b = 0; b < 4; ++b) {
        const float* hp = hb + b * HDIM;
        float hv[64];
#pragma unroll
        for (int j = 0; j < 32; ++j) {
          float2 v = ld_h2_bypass(hp + 2 * j);
          hv[2*j]   = v.x;
          hv[2*j+1] = v.y;
        }
        float acc = 0.f;
#pragma unroll
        for (int j = 0; j < 64; ++j) acc += wh[j] * hv[j];
        ar[b] = acc;
      }
    }

    // Reduce the 4 k-quarters (lanes differ only in kq bits 0..1)
#pragma unroll
    for (int b = 0; b < 4; ++b) {
      float v = ar[b] + px[b];
      v += __shfl_xor(v, 1);
      v += __shfl_xor(v, 2);
      ar[b] = v;
    }
    if (kq == 0) {
#pragma unroll
      for (int b = 0; b < 4; ++b) pre_ex[b][hl][gg] = ar[b] + bias;
    }
    __syncthreads();

    if (tid < 128) {
      const int b = tid >> 5, h2 = tid & 31;
      float4 pg = *(const float4*)(&pre_ex[b][h2][0]);
      float ig = 1.f / (1.f + expf(-pg.x));
      float fg = 1.f / (1.f + expf(-pg.y));
      float og = 1.f / (1.f + expf(-pg.z));
      float cg = tanhf(pg.w);
      creg = fg * creg + ig * cg;
      hreg = og * tanhf(creg);
      const int bgl = b0 + b;
      const int hr  = hs * 32 + h2;
      // write-through store to coherence point; drained by the barrier below
      __hip_atomic_store(
          &hbuf[(size_t)(t & 1) * BATCH * HDIM + (size_t)bgl * HDIM + hr],
          hreg, __ATOMIC_RELAXED, __HIP_MEMORY_SCOPE_AGENT);
    }
    __syncthreads();  // compiler emits s_waitcnt vmcnt(0) before s_barrier:
                      // all h stores are globally visible past this point
    if (tid == 0) {
      __hip_atomic_store(&flags[bid], (unsigned)(t + 1), __ATOMIC_RELAXED,
                         __HIP_MEMORY_SCOPE_AGENT);
    }

    // ---- everything below is OFF the inter-block critical path ----

    // h_seq output store (nobody reads it during the kernel)
    if (tid < 128) {
      const int b = tid >> 5, h2 = tid & 31;
      out[(size_t)t * BATCH * HDIM + (size_t)(b0 + b) * HDIM + (hs * 32 + h2)] = hreg;
    }

    // x-projection for step t+1 — overlaps remote flag/h propagation
    {
      const int tn = (t + 1 < S_LEN) ? (t + 1) : (S_LEN - 1);
      const float* xb = x + ((size_t)tn * BATCH + b0) * IDIM + kq * 64;
#pragma unroll
      for (int b = 0; b < 4; ++b) {
        const float4* p = (const float4*)(xb + b * IDIM);
        float acc = 0.f;
#pragma unroll
        for (int j = 0; j < 16; ++j) {
          float4 v = p[j];
          acc += wx[4*j+0] * v.x; acc += wx[4*j+1] * v.y;
          acc += wx[4*j+2] * v.z; acc += wx[4*j+3] * v.w;
        }
        px[b] = acc;
      }
    }
  }

  // Final (h, c) outputs
  if (tid < 128) {
    const int b = tid >> 5, h2 = tid & 31;
    const int bgl = b0 + b;
    const int hr  = hs * 32 + h2;
    float* oh = out + (size_t)S_LEN * BATCH * HDIM;
    oh[(size_t)bgl * HDIM + hr] = hreg;
    oh[(size_t)BATCH * HDIM + (size_t)bgl * HDIM + hr] = creg;
  }
}

extern "C" void kernel_launch(void* const* d_in, const int* in_sizes, int n_in,
                              void* d_out, int out_size, void* d_ws, size_t ws_size,
                              hipStream_t stream) {
  const float* x   = (const float*)d_in[0];
  const float* Wxi = (const float*)d_in[1];
  const float* Whi = (const float*)d_in[2];
  const float* bxi = (const float*)d_in[3];
  const float* bhi = (const float*)d_in[4];
  const float* Wxf = (const float*)d_in[5];
  const float* Whf = (const float*)d_in[6];
  const float* bxf = (const float*)d_in[7];
  const float* bhf = (const float*)d_in[8];
  const float* Wxo = (const float*)d_in[9];
  const float* Who = (const float*)d_in[10];
  const float* bxo = (const float*)d_in[11];
  const float* bho = (const float*)d_in[12];
  const float* Wxc = (const float*)d_in[13];
  const float* Whc = (const float*)d_in[14];
  const float* bxc = (const float*)d_in[15];
  const float* bhc = (const float*)d_in[16];

  float* out = (float*)d_out;
  float* hbuf = (float*)d_ws;
  unsigned int* flags = (unsigned int*)((char*)d_ws + (size_t)2 * BATCH * HDIM * sizeof(float));

  // zero h exchange buffers (h0 = 0) and flags; ws is re-poisoned 0xAA before every launch
  hipMemsetAsync(d_ws, 0,
                 (size_t)2 * BATCH * HDIM * sizeof(float) + 256 * sizeof(unsigned int),
                 stream);

  lstm_persist<<<dim3(256), dim3(512), 0, stream>>>(
      x, Wxi, Whi, bxi, bhi, Wxf, Whf, bxf, bhf,
      Wxo, Who, bxo, bho, Wxc, Whc, bxc, bhc,
      out, hbuf, flags);
}

// Round 4
// 31172.046 us; speedup vs baseline: 3.4212x; 1.4096x over previous
//
#include <hip/hip_runtime.h>
#include <hip/hip_bf16.h>

#define S_LEN 1024
#define BATCH 128
#define HDIM  256
#define IDIM  256

// Persistent fused LSTM, round 4.
// vs round 3: (1) h exchange de-duplicated -- 512 threads stage the block's
// 4x256 h values ONCE into LDS (2 x 8B bypass loads/thread = 8KB/block/step,
// was 512KB/block/step of redundant uncached reads); matvec reads LDS.
// (2) no flags: h is exchanged as 8B atomic (float h, uint tag=t+1) pairs --
// consumers poll the pair itself until tag >= t. Removes the producer flag
// store + barrier and one full MALL round-trip from the critical path.
// Two-slot ping-pong; a producer cannot overwrite slot s with tag t+3 until
// every peer passed its tag>=t+1 poll of slot s (poll-all-cols ordering), so
// no ABA/lap hazard.
//
// grid = 256 blocks (1 per CU, co-resident -> spin is safe).
// bg = bid & 31 : batch group (4 batch rows); 8 blocks per group share bg.
// hs = bid >> 5 : h-slice of 32 rows.
// block = 512 threads: tid = hl*16 + gg*4 + kq.
// Weight slices pinned in VGPRs (128 floats/thread).

__global__ __launch_bounds__(512) void lstm_persist(
    const float* __restrict__ x,
    const float* __restrict__ Wxi, const float* __restrict__ Whi,
    const float* __restrict__ bxi, const float* __restrict__ bhi,
    const float* __restrict__ Wxf, const float* __restrict__ Whf,
    const float* __restrict__ bxf, const float* __restrict__ bhf,
    const float* __restrict__ Wxo, const float* __restrict__ Who,
    const float* __restrict__ bxo, const float* __restrict__ bho,
    const float* __restrict__ Wxc, const float* __restrict__ Whc,
    const float* __restrict__ bxc, const float* __restrict__ bhc,
    float* __restrict__ out,              // h_seq (S,B,H) then h(B,H) then c(B,H)
    unsigned long long* __restrict__ hpair) // ws: 2 * B * H pairs (8B), zeroed
{
  const int bid = blockIdx.x;
  const int bg  = bid & 31;
  const int hs  = bid >> 5;
  const int tid = threadIdx.x;
  const int hl  = tid >> 4;
  const int gg  = (tid >> 2) & 3;
  const int kq  = tid & 3;
  const int hrow = hs * 32 + hl;
  const int b0   = bg * 4;

  // staging assignment: thread handles pairs (bl, col) and (bl+2, col)
  const int bl  = tid >> 8;     // 0..1
  const int col = tid & 255;    // 0..255

  const float* Wh = (gg == 0) ? Whi : (gg == 1) ? Whf : (gg == 2) ? Who : Whc;
  const float* Wx = (gg == 0) ? Wxi : (gg == 1) ? Wxf : (gg == 2) ? Wxo : Wxc;
  const float* bx = (gg == 0) ? bxi : (gg == 1) ? bxf : (gg == 2) ? bxo : bxc;
  const float* bh = (gg == 0) ? bhi : (gg == 1) ? bhf : (gg == 2) ? bho : bhc;
  const float bias = bx[hrow] + bh[hrow];

  // Pin weight slices in registers (static indexing only).
  float wh[64], wx[64];
  {
    const float4* pwh = (const float4*)(Wh + hrow * HDIM + kq * 64);
    const float4* pwx = (const float4*)(Wx + hrow * IDIM + kq * 64);
#pragma unroll
    for (int j = 0; j < 16; ++j) {
      float4 a = pwh[j];
      wh[4*j+0] = a.x; wh[4*j+1] = a.y; wh[4*j+2] = a.z; wh[4*j+3] = a.w;
      float4 b = pwx[j];
      wx[4*j+0] = b.x; wx[4*j+1] = b.y; wx[4*j+2] = b.z; wx[4*j+3] = b.w;
    }
  }

  __shared__ float h_lds[4][HDIM];    // staged h_prev for this batch group
  __shared__ float pre_ex[4][32][4];  // [b][hl][gate]

  // x-projection partial for t = 0 (normal cached loads)
  float px[4];
  {
    const float* xb = x + (size_t)b0 * IDIM + kq * 64;
#pragma unroll
    for (int b = 0; b < 4; ++b) {
      const float4* p = (const float4*)(xb + b * IDIM);
      float acc = 0.f;
#pragma unroll
      for (int j = 0; j < 16; ++j) {
        float4 v = p[j];
        acc += wx[4*j+0] * v.x; acc += wx[4*j+1] * v.y;
        acc += wx[4*j+2] * v.z; acc += wx[4*j+3] * v.w;
      }
      px[b] = acc;
    }
  }

  float creg = 0.f, hreg = 0.f;

  for (int t = 0; t < S_LEN; ++t) {
    // --- 1. poll + stage h_prev into LDS (tag-carrying pairs) ---
    {
      const size_t sbase = (size_t)((t & 1) ^ 1) * BATCH * HDIM;
      const unsigned long long* hp0 = hpair + sbase + (size_t)(b0 + bl) * HDIM + col;
      const unsigned long long* hp1 = hpair + sbase + (size_t)(b0 + bl + 2) * HDIM + col;
      const unsigned tg = (unsigned)t;
      unsigned long long u0, u1;
      long cnt = 0;
      for (;;) {
        u0 = __hip_atomic_load(hp0, __ATOMIC_RELAXED, __HIP_MEMORY_SCOPE_AGENT);
        u1 = __hip_atomic_load(hp1, __ATOMIC_RELAXED, __HIP_MEMORY_SCOPE_AGENT);
        if (((unsigned)(u0 >> 32) >= tg) & ((unsigned)(u1 >> 32) >= tg)) break;
        if (++cnt > 10000000L) break;  // bailout: terminating beats deadlock
      }
      h_lds[bl][col]     = __uint_as_float((unsigned)u0);
      h_lds[bl + 2][col] = __uint_as_float((unsigned)u1);
    }
    __syncthreads();  // B1: h_lds ready (also orders prev-iter pre_ex reads)

    // --- 2. recurrent matvec from LDS + k-quarter reduce ---
    float ar[4];
#pragma unroll
    for (int b = 0; b < 4; ++b) {
      const float4* hp = (const float4*)&h_lds[b][kq * 64];
      float acc = 0.f;
#pragma unroll
      for (int j = 0; j < 16; ++j) {
        float4 v = hp[j];
        acc += wh[4*j+0] * v.x; acc += wh[4*j+1] * v.y;
        acc += wh[4*j+2] * v.z; acc += wh[4*j+3] * v.w;
      }
      ar[b] = acc;
    }
#pragma unroll
    for (int b = 0; b < 4; ++b) {
      float v = ar[b] + px[b];
      v += __shfl_xor(v, 1);
      v += __shfl_xor(v, 2);
      ar[b] = v;
    }
    if (kq == 0) {
#pragma unroll
      for (int b = 0; b < 4; ++b) pre_ex[b][hl][gg] = ar[b] + bias;
    }
    __syncthreads();  // B2: pre_ex ready

    // --- 3. gates + h/c update + publish (tid < 128) ---
    if (tid < 128) {
      const int b = tid >> 5, h2 = tid & 31;
      float4 pg = *(const float4*)(&pre_ex[b][h2][0]);
      float ig = 1.f / (1.f + expf(-pg.x));
      float fg = 1.f / (1.f + expf(-pg.y));
      float og = 1.f / (1.f + expf(-pg.z));
      float cg = tanhf(pg.w);
      creg = fg * creg + ig * cg;
      hreg = og * tanhf(creg);
      const int bgl = b0 + b;
      const int hr  = hs * 32 + h2;
      const unsigned long long u =
          ((unsigned long long)(unsigned)(t + 1) << 32) |
          (unsigned long long)__float_as_uint(hreg);
      __hip_atomic_store(
          &hpair[(size_t)(t & 1) * BATCH * HDIM + (size_t)bgl * HDIM + hr],
          u, __ATOMIC_RELAXED, __HIP_MEMORY_SCOPE_AGENT);
      // h_seq output (nobody reads during kernel; normal cached store)
      out[(size_t)t * BATCH * HDIM + (size_t)bgl * HDIM + hr] = hreg;
    }

    // --- 4. x-projection for t+1 (overlaps remote pair propagation) ---
    {
      const int tn = (t + 1 < S_LEN) ? (t + 1) : (S_LEN - 1);
      const float* xb = x + ((size_t)tn * BATCH + b0) * IDIM + kq * 64;
#pragma unroll
      for (int b = 0; b < 4; ++b) {
        const float4* p = (const float4*)(xb + b * IDIM);
        float acc = 0.f;
#pragma unroll
        for (int j = 0; j < 16; ++j) {
          float4 v = p[j];
          acc += wx[4*j+0] * v.x; acc += wx[4*j+1] * v.y;
          acc += wx[4*j+2] * v.z; acc += wx[4*j+3] * v.w;
        }
        px[b] = acc;
      }
    }
  }

  // Final (h, c) outputs
  if (tid < 128) {
    const int b = tid >> 5, h2 = tid & 31;
    const int bgl = b0 + b;
    const int hr  = hs * 32 + h2;
    float* oh = out + (size_t)S_LEN * BATCH * HDIM;
    oh[(size_t)bgl * HDIM + hr] = hreg;
    oh[(size_t)BATCH * HDIM + (size_t)bgl * HDIM + hr] = creg;
  }
}

extern "C" void kernel_launch(void* const* d_in, const int* in_sizes, int n_in,
                              void* d_out, int out_size, void* d_ws, size_t ws_size,
                              hipStream_t stream) {
  const float* x   = (const float*)d_in[0];
  const float* Wxi = (const float*)d_in[1];
  const float* Whi = (const float*)d_in[2];
  const float* bxi = (const float*)d_in[3];
  const float* bhi = (const float*)d_in[4];
  const float* Wxf = (const float*)d_in[5];
  const float* Whf = (const float*)d_in[6];
  const float* bxf = (const float*)d_in[7];
  const float* bhf = (const float*)d_in[8];
  const float* Wxo = (const float*)d_in[9];
  const float* Who = (const float*)d_in[10];
  const float* bxo = (const float*)d_in[11];
  const float* bho = (const float*)d_in[12];
  const float* Wxc = (const float*)d_in[13];
  const float* Whc = (const float*)d_in[14];
  const float* bxc = (const float*)d_in[15];
  const float* bhc = (const float*)d_in[16];

  float* out = (float*)d_out;
  unsigned long long* hpair = (unsigned long long*)d_ws;

  // zero pair buffers: h0 = 0, tags = 0 (t=0 poll passes immediately).
  // ws re-poisoned 0xAA before every launch -> must re-zero every call.
  hipMemsetAsync(d_ws, 0, (size_t)2 * BATCH * HDIM * sizeof(unsigned long long),
                 stream);

  lstm_persist<<<dim3(256), dim3(512), 0, stream>>>(
      x, Wxi, Whi, bxi, bhi, Wxf, Whf, bxf, bhf,
      Wxo, Who, bxo, bho, Wxc, Whc, bxc, bhc,
      out, hpair);
}

// Round 6
// 7447.418 us; speedup vs baseline: 14.3197x; 4.1856x over previous
//
#include <hip/hip_runtime.h>
#include <hip/hip_bf16.h>

#define S_LEN 1024
#define BATCH 128
#define HDIM  256
#define IDIM  256

// Persistent fused LSTM, round 6 (= round 5 resubmitted; infra failure, never ran).
// vs round 4:
//  (1) poll SMALL flags (8 pollers x 4B, 64B-strided), bulk h data read ONCE
//      after flags pass  -> kills the 39GB of poll-retry fabric reads.
//  (2) register-tiled matvec: thread = 4 gh-rows x 16-k-slice; each LDS float
//      feeds 16 FMAs -> LDS traffic 8x down (512KB -> 128KB/block/step).
//      k-column rotation ((kq>>1)+j) makes ds_read_b128 2-way-per-bank = free;
//      pinned weights are loaded in the SAME rotated order so FMAs align.
//  (3) 15-shfl recursive-halving reduce-scatter over the 16 k-lanes; lane kq
//      ends with output i=kq (i = b + 4r), one ds_write_b32 into pre_lds[4][129].
// Sync protocol (proven in r3/r4): relaxed agent-scope atomics
// (global_load/store sc0 sc1, no cache maintenance); producer h-stores drained
// by the s_waitcnt vmcnt(0) each wave executes at __syncthreads before tid0
// sets its flag; consumers poll flags then load h. Two-slot ping-pong; writer
// of slot p at step t+2 is gated (via flags>=t+2) behind all peers' stage-reads
// of slot p at t+1 -> no overwrite hazard.
//
// grid = 256 blocks (1/CU, co-resident). bg = bid&31 (4 batch rows),
// hs = bid>>5 (32 h-rows). 8 blocks of a group share bid%8 -> same XCD.
// block = 512 threads: tid = hh*16 + kq (hh 0..31 row-group, kq 0..15 k-slice).

__global__ __launch_bounds__(512) void lstm_persist(
    const float* __restrict__ x,
    const float* __restrict__ Wxi, const float* __restrict__ Whi,
    const float* __restrict__ bxi, const float* __restrict__ bhi,
    const float* __restrict__ Wxf, const float* __restrict__ Whf,
    const float* __restrict__ bxf, const float* __restrict__ bhf,
    const float* __restrict__ Wxo, const float* __restrict__ Who,
    const float* __restrict__ bxo, const float* __restrict__ bho,
    const float* __restrict__ Wxc, const float* __restrict__ Whc,
    const float* __restrict__ bxc, const float* __restrict__ bhc,
    float* __restrict__ out,            // h_seq (S,B,H) then h(B,H) then c(B,H)
    float* __restrict__ hslot,          // ws: 2 * B * H floats, zeroed
    unsigned int* __restrict__ flags)   // ws: 256 * 16 u32 (64B stride), zeroed
{
  const int bid = blockIdx.x;
  const int bg  = bid & 31;
  const int hs  = bid >> 5;
  const int tid = threadIdx.x;
  const int hh  = tid >> 4;   // 0..31 : group of 4 gh-rows
  const int kq  = tid & 15;   // 0..15 : 16-wide k-slice
  const int b0  = bg * 4;

  // rotated k-columns for this thread's slice: 2-way banks on ds_read_b128
  int col4[4];
#pragma unroll
  for (int j = 0; j < 4; ++j) col4[j] = kq * 16 + 4 * (((kq >> 1) + j) & 3);

  // pin weights: 4 rows x 16 k (rotated order) for Wh and Wx = 128 VGPRs
  float wh[4][16], wx[4][16];
#pragma unroll
  for (int r = 0; r < 4; ++r) {
    const int ghrow = hh * 4 + r;          // 0..127 = g*32 + hl
    const int g     = ghrow >> 5;
    const int hrow  = hs * 32 + (ghrow & 31);
    const float* Whp = (g == 0) ? Whi : (g == 1) ? Whf : (g == 2) ? Who : Whc;
    const float* Wxp = (g == 0) ? Wxi : (g == 1) ? Wxf : (g == 2) ? Wxo : Wxc;
#pragma unroll
    for (int j = 0; j < 4; ++j) {
      float4 a = *(const float4*)(Whp + (size_t)hrow * HDIM + col4[j]);
      wh[r][4*j+0] = a.x; wh[r][4*j+1] = a.y; wh[r][4*j+2] = a.z; wh[r][4*j+3] = a.w;
      float4 c = *(const float4*)(Wxp + (size_t)hrow * IDIM + col4[j]);
      wx[r][4*j+0] = c.x; wx[r][4*j+1] = c.y; wx[r][4*j+2] = c.z; wx[r][4*j+3] = c.w;
    }
  }

  // combine-thread identity (tid<128): b = tid>>5, h2 = tid&31; biases pinned
  const int cb  = tid >> 5;        // valid (<4) only when tid<128
  const int ch2 = tid & 31;
  const int chrow = hs * 32 + ch2;
  const float bias_i = bxi[chrow] + bhi[chrow];
  const float bias_f = bxf[chrow] + bhf[chrow];
  const float bias_o = bxo[chrow] + bho[chrow];
  const float bias_c = bxc[chrow] + bhc[chrow];

  // staging assignment: one 8B load per thread covers 4x256 floats
  const int srow = tid >> 7;          // 0..3
  const int scol = (tid & 127) * 2;   // 0..254 even

  __shared__ float h_lds[4][HDIM];
  __shared__ float pre_lds[4][129];   // +1 word stride: spreads b over banks

  float acc[16];  // acc[b + 4*r]

  // prologue: acc = Wx . x[0]
  {
    const float* xb = x + (size_t)b0 * IDIM;
#pragma unroll
    for (int i = 0; i < 16; ++i) acc[i] = 0.f;
#pragma unroll
    for (int j = 0; j < 4; ++j)
#pragma unroll
      for (int b = 0; b < 4; ++b) {
        float4 v = *(const float4*)(xb + b * IDIM + col4[j]);
#pragma unroll
        for (int r = 0; r < 4; ++r)
          acc[b + 4*r] += wx[r][4*j+0]*v.x + wx[r][4*j+1]*v.y
                        + wx[r][4*j+2]*v.z + wx[r][4*j+3]*v.w;
      }
  }

  float creg = 0.f, hreg = 0.f;

  for (int t = 0; t < S_LEN; ++t) {
    // --- 1. poll producer flags (tiny traffic: 8 threads x 4B) ---
    if (tid < 8) {
      const unsigned tgt = (unsigned)t;
      long cnt = 0;
      while (__hip_atomic_load(&flags[(tid * 32 + bg) * 16], __ATOMIC_RELAXED,
                               __HIP_MEMORY_SCOPE_AGENT) < tgt) {
        if (++cnt > 50000000L) break;  // terminating beats deadlock
      }
    }
    __syncthreads();  // B1: flags passed for all

    // --- 2. stage h_prev once: 512 threads x one 8B bypass load ---
    {
      const float* src = hslot + (size_t)((t & 1) ^ 1) * BATCH * HDIM
                       + (size_t)(b0 + srow) * HDIM + scol;
      unsigned long long u = __hip_atomic_load(
          (const unsigned long long*)src, __ATOMIC_RELAXED,
          __HIP_MEMORY_SCOPE_AGENT);
      h_lds[srow][scol]     = __uint_as_float((unsigned)u);
      h_lds[srow][scol + 1] = __uint_as_float((unsigned)(u >> 32));
    }
    __syncthreads();  // B2: h_lds ready

    // --- 3. register-tiled matvec: acc += Wh . h  (16 FMA per LDS float4) ---
#pragma unroll
    for (int j = 0; j < 4; ++j)
#pragma unroll
      for (int b = 0; b < 4; ++b) {
        const float4 v = *(const float4*)&h_lds[b][col4[j]];
#pragma unroll
        for (int r = 0; r < 4; ++r)
          acc[b + 4*r] += wh[r][4*j+0]*v.x + wh[r][4*j+1]*v.y
                        + wh[r][4*j+2]*v.z + wh[r][4*j+3]*v.w;
      }

    // --- 4. reduce-scatter over 16 kq-lanes (15 shfl): lane kq -> output kq ---
    float s;
    {
      float a8[8];
      { const int bit = kq & 1;
#pragma unroll
        for (int j = 0; j < 8; ++j) {
          float keep = bit ? acc[2*j+1] : acc[2*j];
          float send = bit ? acc[2*j]   : acc[2*j+1];
          a8[j] = keep + __shfl_xor(send, 1);
        } }
      float a4[4];
      { const int bit = (kq >> 1) & 1;
#pragma unroll
        for (int j = 0; j < 4; ++j) {
          float keep = bit ? a8[2*j+1] : a8[2*j];
          float send = bit ? a8[2*j]   : a8[2*j+1];
          a4[j] = keep + __shfl_xor(send, 2);
        } }
      float a2[2];
      { const int bit = (kq >> 2) & 1;
#pragma unroll
        for (int j = 0; j < 2; ++j) {
          float keep = bit ? a4[2*j+1] : a4[2*j];
          float send = bit ? a4[2*j]   : a4[2*j+1];
          a2[j] = keep + __shfl_xor(send, 4);
        } }
      { const int bit = (kq >> 3) & 1;
        float keep = bit ? a2[1] : a2[0];
        float send = bit ? a2[0] : a2[1];
        s = keep + __shfl_xor(send, 8);
      }
    }
    // lane kq holds output i=kq: b = kq&3, r = kq>>2; row = hh*4 + r
    pre_lds[kq & 3][hh * 4 + (kq >> 2)] = s;
    __syncthreads();  // B3: pre_lds ready

    // --- 5. combine gates + publish h (tid < 128) ---
    if (tid < 128) {
      float gi = pre_lds[cb][0*32 + ch2] + bias_i;
      float gf = pre_lds[cb][1*32 + ch2] + bias_f;
      float go = pre_lds[cb][2*32 + ch2] + bias_o;
      float gc = pre_lds[cb][3*32 + ch2] + bias_c;
      float ig = 1.f / (1.f + expf(-gi));
      float fg = 1.f / (1.f + expf(-gf));
      float og = 1.f / (1.f + expf(-go));
      float cg = tanhf(gc);
      creg = fg * creg + ig * cg;
      hreg = og * tanhf(creg);
      const int bgl = b0 + cb;
      __hip_atomic_store(
          &hslot[(size_t)(t & 1) * BATCH * HDIM + (size_t)bgl * HDIM + chrow],
          hreg, __ATOMIC_RELAXED, __HIP_MEMORY_SCOPE_AGENT);
      out[(size_t)t * BATCH * HDIM + (size_t)bgl * HDIM + chrow] = hreg;
    }
    __syncthreads();  // B4: each wave drained its stores (vmcnt 0) -> visible
    if (tid == 0) {
      __hip_atomic_store(&flags[bid * 16], (unsigned)(t + 1), __ATOMIC_RELAXED,
                         __HIP_MEMORY_SCOPE_AGENT);
    }

    // --- 6. x-projection for t+1 (off the inter-block critical path) ---
    {
      const int tn = (t + 1 < S_LEN) ? (t + 1) : (S_LEN - 1);
      const float* xb = x + ((size_t)tn * BATCH + b0) * IDIM;
#pragma unroll
      for (int i = 0; i < 16; ++i) acc[i] = 0.f;
#pragma unroll
      for (int j = 0; j < 4; ++j)
#pragma unroll
        for (int b = 0; b < 4; ++b) {
          float4 v = *(const float4*)(xb + b * IDIM + col4[j]);
#pragma unroll
          for (int r = 0; r < 4; ++r)
            acc[b + 4*r] += wx[r][4*j+0]*v.x + wx[r][4*j+1]*v.y
                          + wx[r][4*j+2]*v.z + wx[r][4*j+3]*v.w;
        }
    }
  }

  // final (h, c)
  if (tid < 128) {
    float* oh = out + (size_t)S_LEN * BATCH * HDIM;
    const int bgl = b0 + cb;
    oh[(size_t)bgl * HDIM + chrow] = hreg;
    oh[(size_t)BATCH * HDIM + (size_t)bgl * HDIM + chrow] = creg;
  }
}

extern "C" void kernel_launch(void* const* d_in, const int* in_sizes, int n_in,
                              void* d_out, int out_size, void* d_ws, size_t ws_size,
                              hipStream_t stream) {
  const float* x   = (const float*)d_in[0];
  const float* Wxi = (const float*)d_in[1];
  const float* Whi = (const float*)d_in[2];
  const float* bxi = (const float*)d_in[3];
  const float* bhi = (const float*)d_in[4];
  const float* Wxf = (const float*)d_in[5];
  const float* Whf = (const float*)d_in[6];
  const float* bxf = (const float*)d_in[7];
  const float* bhf = (const float*)d_in[8];
  const float* Wxo = (const float*)d_in[9];
  const float* Who = (const float*)d_in[10];
  const float* bxo = (const float*)d_in[11];
  const float* bho = (const float*)d_in[12];
  const float* Wxc = (const float*)d_in[13];
  const float* Whc = (const float*)d_in[14];
  const float* bxc = (const float*)d_in[15];
  const float* bhc = (const float*)d_in[16];

  float* out = (float*)d_out;
  float* hslot = (float*)d_ws;
  unsigned int* flags =
      (unsigned int*)((char*)d_ws + (size_t)2 * BATCH * HDIM * sizeof(float));

  // zero h slots (h0 = 0, incl. slot 1 read at t=0) and flags; ws is
  // re-poisoned 0xAA before every launch -> must re-zero every call.
  hipMemsetAsync(d_ws, 0,
                 (size_t)2 * BATCH * HDIM * sizeof(float) +
                     (size_t)256 * 16 * sizeof(unsigned int),
                 stream);

  lstm_persist<<<dim3(256), dim3(512), 0, stream>>>(
      x, Wxi, Whi, bxi, bhi, Wxf, Whf, bxf, bhf,
      Wxo, Who, bxo, bho, Wxc, Whc, bxc, bhc,
      out, hslot, flags);
}